// Round 14
// baseline (175.308 us; speedup 1.0000x reference)
//
#include <hip/hip_runtime.h>

#define N_V   8192
#define CAP   96          // max neighbors kept (deg ~Binom(8192,16/8192): mean 16; P(>=96)~0)
#define NF    128
#define TBL_PROWS 1029    // partial rows: L1 784 + L2 196 + L3 49

typedef __attribute__((ext_vector_type(4))) float f32x4;
typedef __attribute__((ext_vector_type(8))) short b16x8;

__device__ __forceinline__ short f2bf(float f) {
    unsigned u = __builtin_bit_cast(unsigned, f);
    unsigned r = u + 0x7FFFu + ((u >> 16) & 1u);
    return (short)(r >> 16);
}
__device__ __forceinline__ float bf2f(short h) {
    return __builtin_bit_cast(float, ((unsigned)(unsigned short)h) << 16);
}
__device__ __forceinline__ float4 f4add(float4 a, float4 b) {
    return make_float4(a.x + b.x, a.y + b.y, a.z + b.z, a.w + b.w);
}
__device__ __forceinline__ float2 f2add(float2 a, float2 b) {
    return make_float2(a.x + b.x, a.y + b.y);
}

// ---- shared csr row-scan body: one wave processes row n ----
__device__ __forceinline__ void csr_row(const float* __restrict__ adj,
                                        int* __restrict__ cnt,
                                        int* __restrict__ nbr,
                                        int n, int lane)
{
    const float4* r4 = reinterpret_cast<const float4*>(adj + (size_t)n * N_V);
    int* row = nbr + (size_t)n * CAP;
    int base = 0;
    unsigned long long below = (1ull << lane) - 1ull;
    for (int it = 0; it < N_V / 256; ++it) {
        float4 v = r4[it * 64 + lane];
        unsigned long long m0 = __ballot(v.x != 0.f);
        unsigned long long m1 = __ballot(v.y != 0.f);
        unsigned long long m2 = __ballot(v.z != 0.f);
        unsigned long long m3 = __ballot(v.w != 0.f);
        int p = base + __popcll(m0 & below) + __popcll(m1 & below)
                     + __popcll(m2 & below) + __popcll(m3 & below);
        int col = it * 256 + lane * 4;
        if (v.x != 0.f && p < CAP) row[p++] = col;
        if (v.y != 0.f && p < CAP) row[p++] = col + 1;
        if (v.z != 0.f && p < CAP) row[p++] = col + 2;
        if (v.w != 0.f && p < CAP) row[p++] = col + 3;
        base += __popcll(m0) + __popcll(m1) + __popcll(m2) + __popcll(m3);
    }
    if (lane == 0) cnt[n] = (base < CAP) ? base : CAP;
}

// ============ kernel A: csr rows 0..4607 (blocks 0..575, 8 rows) | table GEMM (576..767) | wprep (768..834) ============
__global__ __launch_bounds__(512, 8) void prep_csrA_kernel(const float* __restrict__ adj,
                                                           int* __restrict__ cnt,
                                                           int* __restrict__ nbr,
                                                           const float* __restrict__ f0,
                                                           const float* __restrict__ f1,
                                                           const float* __restrict__ f2,
                                                           const float* __restrict__ f3,
                                                           const float* __restrict__ lin_w,
                                                           float* __restrict__ table,
                                                           float* __restrict__ partial,
                                                           const float* rg0_c0_w0, const float* rg0_c0_w1, const float* rg0_proj,
                                                           const float* rg0_c1_w0, const float* rg0_c1_w1,
                                                           const float* rg1_c0_w0, const float* rg1_c0_w1,
                                                           const float* rg1_c1_w0, const float* rg1_c1_w1,
                                                           const float* rg2_c0_w0, const float* rg2_c0_w1,
                                                           const float* rg2_c1_w0, const float* rg2_c1_w1,
                                                           unsigned short* __restrict__ WHu,
                                                           unsigned short* __restrict__ WLu)
{
    __shared__ __align__(16) float sF[32][36];
    __shared__ __align__(16) float sW[32][NF];

    int tid  = threadIdx.x;
    int wv   = tid >> 6, lane = tid & 63;

    if (blockIdx.x < 576) {
        csr_row(adj, cnt, nbr, blockIdx.x * 8 + wv, lane);
        return;
    }

    if (blockIdx.x < 768) {
        // ---- table split-K GEMM, 512-thread layout (2 p-rows/thread) ----
        int b = blockIdx.x - 576;
        int l, pb, kc;
        if      (b < 98)  { l = 0; pb = b;       kc = 0;                     }
        else if (b < 148) { int t = b - 98;  l = 1; pb = t >> 1; kc = t & 1; }
        else if (b < 176) { int t = b - 148; l = 2; pb = t >> 2; kc = t & 3; }
        else              { int t = b - 176; l = 3; pb = t >> 3; kc = t & 7; }
        const float* f = (l == 0) ? f0 : (l == 1) ? f1 : (l == 2) ? f2 : f3;
        int P      = (l == 0) ? 3136 : (l == 1) ? 784 : (l == 2) ? 196 : 49;
        int rowoff = (l == 0) ? 0 : (l == 1) ? 256 : (l == 2) ? 768 : 1792;
        int rel0   = (l == 1) ? 0 : (l == 2) ? 784 : 980;
        int p0c    = pb * 32;
        int kbeg   = kc * 256;

        int ty = tid >> 5;             // 0..15 -> 2 p each
        int tx = tid & 31;             // 4 j each
        float4 acc0 = make_float4(0.f, 0.f, 0.f, 0.f), acc1 = acc0;

        #pragma unroll 1
        for (int ks = 0; ks < 8; ++ks) {
            int k0 = kbeg + ks * 32;
            #pragma unroll
            for (int t2 = 0; t2 < 2; ++t2) {
                int idx = tid + t2 * 512;
                int c = idx >> 5, pp = idx & 31;
                int p = p0c + pp;
                sF[c][pp] = (p < P) ? f[(size_t)(k0 + c) * P + p] : 0.f;
            }
            {
                const float4* lw4 = (const float4*)(lin_w + (size_t)(rowoff + k0) * NF);
                #pragma unroll
                for (int t2 = 0; t2 < 2; ++t2) {
                    int idx = tid + t2 * 512;
                    int kr = idx >> 5, c4 = idx & 31;
                    *(float4*)&sW[kr][c4 * 4] = lw4[(size_t)kr * 32 + c4];
                }
            }
            __syncthreads();
            #pragma unroll
            for (int kk = 0; kk < 32; ++kk) {
                float4 wv4 = *(const float4*)&sW[kk][tx * 4];
                float a0 = sF[kk][ty * 2];
                float a1 = sF[kk][ty * 2 + 1];
                acc0.x += a0 * wv4.x; acc0.y += a0 * wv4.y; acc0.z += a0 * wv4.z; acc0.w += a0 * wv4.w;
                acc1.x += a1 * wv4.x; acc1.y += a1 * wv4.y; acc1.z += a1 * wv4.z; acc1.w += a1 * wv4.w;
            }
            __syncthreads();
        }
        #pragma unroll
        for (int i = 0; i < 2; ++i) {
            int p = p0c + ty * 2 + i;
            if (p < P) {
                float4 o = i ? acc1 : acc0;
                if (l == 0) *(float4*)&table[(size_t)p * NF + tx * 4] = o;
                else        *(float4*)&partial[((size_t)kc * TBL_PROWS + rel0 + p) * NF + tx * 4] = o;
            }
        }
        return;
    }

    // ---- weight prep: split-bf16, MFMA-frag order (one task per block, 512-thread stride) ----
    {
        const float* k128s[10] = { rg0_c1_w0, rg0_c1_w1, rg1_c0_w0, rg1_c0_w1, rg1_c1_w0,
                                   rg1_c1_w1, rg2_c0_w0, rg2_c0_w1, rg2_c1_w0, rg2_c1_w1 };
        const float* k288s[3]  = { rg0_c0_w0, rg0_c0_w1, rg0_proj };
        int b = blockIdx.x - 768;
        const float* src;
        int K, ks;
        size_t dst;
        if (b < 40) { int m = b >> 2; ks = b & 3;              src = k128s[m]; K = 128; dst = (size_t)m * 16384 + (size_t)ks * 4096; }
        else        { int t = b - 40; int m = t / 9; ks = t % 9; src = k288s[m]; K = 259; dst = 163840 + (size_t)m * 36864 + (size_t)ks * 4096; }
        for (int idx = tid; idx < 4096; idx += 512) {
            int lane2 = (idx >> 3) & 63;
            int i     = idx & 7;
            int nt    = idx >> 9;
            int sk = ks * 32 + ((lane2 >> 4) << 3) + i;
            int sn = (nt << 4) + (lane2 & 15);
            float v = (sk < K) ? src[(size_t)sk * NF + sn] : 0.f;
            short hh = f2bf(v);
            short ll = f2bf(v - bf2f(hh));
            WHu[dst + idx] = (unsigned short)hh;
            WLu[dst + idx] = (unsigned short)ll;
        }
    }
}

// ============ kernel B: csr rows 4608..8191 (blocks 0..447) | a3align (448..959, 16 rows) ============
__global__ __launch_bounds__(512, 8) void align_csrB_kernel(const float* __restrict__ adj,
                                                            int* __restrict__ cnt,
                                                            int* __restrict__ nbr,
                                                            const float* __restrict__ pos,
                                                            const float* __restrict__ vfeat,
                                                            const float* __restrict__ table,
                                                            const float* __restrict__ partial,
                                                            const unsigned short* __restrict__ WHu,
                                                            const unsigned short* __restrict__ WLu,
                                                            float* __restrict__ t0,
                                                            float* __restrict__ t1,
                                                            float* __restrict__ skipb)
{
    __shared__ float sMem[288 * 17];   // 19.6 KB
    __shared__ int   sIdx[16][4];

    int tid = threadIdx.x;
    int wv  = tid >> 6, lane = tid & 63;

    if (blockIdx.x < 448) {
        csr_row(adj, cnt, nbr, 4608 + blockIdx.x * 8 + wv, lane);
        return;
    }

    int row0 = (blockIdx.x - 448) * 16;

    if (tid < 16) {
        int n = row0 + tid;
        float px = pos[(size_t)n * 3 + 0];
        float py = pos[(size_t)n * 3 + 1];
        float pz = pos[(size_t)n * 3 + 2];
        float h = fminf(fmaxf(__fadd_rn(__fmul_rn(248.f, __fdiv_rn(py, pz)),  111.5f), 0.f), 223.f);
        float w = fminf(fmaxf(__fadd_rn(__fmul_rn(248.f, __fdiv_rn(px, -pz)), 111.5f), 0.f), 223.f);
        const int   sxs[4]   = {56, 28, 14, 7};
        const float scl[4]   = {0.25f, 0.125f, 0.0625f, 0.03125f};
        const int   rel0s[4] = {0, 0, 784, 980};
        #pragma unroll
        for (int l = 0; l < 4; ++l) {
            float x = __fmul_rn(w, scl[l]);
            float y = __fmul_rn(h, scl[l]);
            int x1 = (int)floorf(x);
            int x2 = min((int)ceilf(x), sxs[l] - 1);
            int y1 = (int)floorf(y);
            int y2 = min((int)ceilf(y), sxs[l] - 1);
            int xi = (int)x, yi = (int)y;
            int w11 = (x2 - xi) * (y2 - yi);   // in {0,1}
            sIdx[tid][l] = w11 ? (rel0s[l] + x1 * sxs[l] + y1) : -1;
        }
    }
    __syncthreads();
    {
        // coalesced assemble: lane-contiguous c, row r = tid>>5
        int r = tid >> 5, cb = tid & 31;
        int n = row0 + r;
        #pragma unroll 1
        for (int k = 0; k < 9; ++k) {
            int c = cb + k * 32;               // 0..287
            float val;
            if (c < 128) {
                val = vfeat[(size_t)n * NF + c];
            } else if (c < 131) {
                val = pos[(size_t)n * 3 + (c - 128)];
            } else if (c < 259) {
                int jj = c - 131;
                val = 0.f;
                int i0 = sIdx[r][0];
                if (i0 >= 0) val += table[(size_t)i0 * NF + jj];
                #pragma unroll
                for (int l = 1; l < 4; ++l) {
                    int ix = sIdx[r][l];
                    if (ix >= 0) {
                        int nc = (l == 1) ? 2 : (l == 2) ? 4 : 8;
                        for (int cc = 0; cc < nc; ++cc)
                            val += partial[((size_t)cc * TBL_PROWS + ix) * NF + jj];
                    }
                }
            } else {
                val = 0.f;
            }
            sMem[c * 17 + r] = val;
        }
    }
    __syncthreads();
    // 6 waves: (head 0..2) x (nhalf 0..1), 4 nt tiles each
    if (wv < 6) {
        int head = wv >> 1, nh = wv & 1;
        const b16x8* Bh = (const b16x8*)WHu + 20480 + head * 4608;
        const b16x8* Bl = (const b16x8*)WLu + 20480 + head * 4608;
        float* O = (head == 0) ? t0 : (head == 1) ? t1 : skipb;
        f32x4 acc[4] = {};
        int m  = lane & 15;
        int kb = (lane >> 4) << 3;
        #pragma unroll 1
        for (int ks = 0; ks < 9; ++ks) {
            b16x8 va, vl;
            #pragma unroll
            for (int i = 0; i < 8; ++i) {
                float f = sMem[(ks * 32 + kb + i) * 17 + m];
                short hi = f2bf(f);
                va[i] = hi;
                vl[i] = f2bf(f - bf2f(hi));
            }
            #pragma unroll
            for (int t = 0; t < 4; ++t) {
                int nt = nh * 4 + t;
                b16x8 bh = Bh[(ks * 8 + nt) * 64 + lane];
                b16x8 bl = Bl[(ks * 8 + nt) * 64 + lane];
                acc[t] = __builtin_amdgcn_mfma_f32_16x16x32_bf16(va, bh, acc[t], 0, 0, 0);
                acc[t] = __builtin_amdgcn_mfma_f32_16x16x32_bf16(vl, bh, acc[t], 0, 0, 0);
                acc[t] = __builtin_amdgcn_mfma_f32_16x16x32_bf16(va, bl, acc[t], 0, 0, 0);
            }
        }
        int orow = row0 + ((lane >> 4) << 2);
        int oc   = lane & 15;
        #pragma unroll
        for (int t = 0; t < 4; ++t)
            #pragma unroll
            for (int rr = 0; rr < 4; ++rr)
                O[(size_t)(orow + rr) * NF + (nh * 4 + t) * 16 + oc] = acc[t][rr];
    }
}

// ---- build 16-row A-tile, 1024 threads = 16 rows x 64 lanes/row (float2/lane, fully coalesced) ----
// Same per-element accumulation order as before: acc a holds nbr 0,4,8..., b:1,5.., c:2,6.., d:3,7..; (a+b)+(c+d).
__device__ __forceinline__ void build_rows1024(const float* __restrict__ p0,
                                               const float* __restrict__ p1,
                                               const int* __restrict__ cnt,
                                               const int* __restrict__ nbr,
                                               const float* skip,
                                               float* awr,
                                               float* sA, int row0, int tid)
{
    int r  = tid >> 6;                  // 0..15 row (one wave per row)
    int ch = tid & 63;                  // 0..63 -> float2 col (contiguous across lanes)
    int n  = row0 + r;
    float2 a = ((const float2*)(p0 + (size_t)n * NF))[ch];
    float2 b = make_float2(0.f, 0.f), c = b, d = b;
    int cdeg = cnt[n];
    const int*  nb  = nbr + (size_t)n * CAP;
    const int4* nb4 = (const int4*)nb;
    int i = 0;
    for (; i + 4 <= cdeg; i += 4) {
        int4 ix = nb4[i >> 2];
        float2 va = ((const float2*)(p1 + (size_t)ix.x * NF))[ch];
        float2 vb = ((const float2*)(p1 + (size_t)ix.y * NF))[ch];
        float2 vc = ((const float2*)(p1 + (size_t)ix.z * NF))[ch];
        float2 vd = ((const float2*)(p1 + (size_t)ix.w * NF))[ch];
        a = f2add(a, va);
        b = f2add(b, vb);
        c = f2add(c, vc);
        d = f2add(d, vd);
    }
    for (; i < cdeg; ++i)
        a = f2add(a, ((const float2*)(p1 + (size_t)nb[i] * NF))[ch]);
    a = f2add(f2add(a, b), f2add(c, d));
    float v[2] = { a.x, a.y };
    v[0] = fmaxf(v[0], 0.f);
    v[1] = fmaxf(v[1], 0.f);
    if (skip) {
        const float* rs = skip + (size_t)n * NF + ch * 2;
        v[0] += rs[0];
        v[1] += rs[1];
    }
    if (awr) {
        float* wr = awr + (size_t)n * NF + ch * 2;
        wr[0] = v[0];
        wr[1] = v[1];
    }
    sA[(ch * 2 + 0) * 17 + r] = v[0];
    sA[(ch * 2 + 1) * 17 + r] = v[1];
}

// ============ fused SpMM + 2-head MFMA: 512 blocks x 1024 thr (32 waves/CU) ============
// 16 wave-tasks: head (2) x nt (8); each wave one 16x16 output tile, acc = 1 f32x4.
__global__ __launch_bounds__(1024, 8) void fgemm_kernel(const float* __restrict__ p0,
                                                        const float* __restrict__ p1,
                                                        const int* __restrict__ cnt,
                                                        const int* __restrict__ nbr,
                                                        const float* __restrict__ skip,
                                                        float* __restrict__ awr,
                                                        const unsigned short* __restrict__ WHu,
                                                        const unsigned short* __restrict__ WLu,
                                                        int fo0, int fo1,
                                                        float* __restrict__ O0,
                                                        float* __restrict__ O1)
{
    __shared__ float sA[NF * 17];      // 8.7 KB
    int tid  = threadIdx.x;
    int row0 = blockIdx.x * 16;
    build_rows1024(p0, p1, cnt, nbr, skip, awr, sA, row0, tid);
    __syncthreads();

    int wv = tid >> 6, lane = tid & 63;
    int h  = wv >> 3;                  // 0..1 head
    int nt = wv & 7;                   // 0..7 output col-tile
    int fo = h ? fo1 : fo0;
    const b16x8* Bh = (const b16x8*)WHu + fo;
    const b16x8* Bl = (const b16x8*)WLu + fo;
    float* O = h ? O1 : O0;
    f32x4 acc = {};
    int m  = lane & 15;
    int kb = (lane >> 4) << 3;
    #pragma unroll 1
    for (int ks = 0; ks < 4; ++ks) {
        b16x8 va, vl;
        #pragma unroll
        for (int i = 0; i < 8; ++i) {
            float f = sA[(ks * 32 + kb + i) * 17 + m];
            short hi = f2bf(f);
            va[i] = hi;
            vl[i] = f2bf(f - bf2f(hi));
        }
        b16x8 bh = Bh[(ks * 8 + nt) * 64 + lane];
        b16x8 bl = Bl[(ks * 8 + nt) * 64 + lane];
        acc = __builtin_amdgcn_mfma_f32_16x16x32_bf16(va, bh, acc, 0, 0, 0);
        acc = __builtin_amdgcn_mfma_f32_16x16x32_bf16(vl, bh, acc, 0, 0, 0);
        acc = __builtin_amdgcn_mfma_f32_16x16x32_bf16(va, bl, acc, 0, 0, 0);
    }
    int orow = row0 + ((lane >> 4) << 2);
    int oc   = lane & 15;
    #pragma unroll
    for (int rr = 0; rr < 4; ++rr)
        O[(size_t)(orow + rr) * NF + nt * 16 + oc] = acc[rr];
}

// ============ final: x3 -> out1; g0 = x3@gw0, g1 = x3@gw1 ============
__global__ __launch_bounds__(1024, 8) void fgemm_final_kernel(const float* __restrict__ p0,
                                                              const float* __restrict__ p1,
                                                              const int* __restrict__ cnt,
                                                              const int* __restrict__ nbr,
                                                              const float* __restrict__ skip,
                                                              float* __restrict__ awr,   // out1
                                                              const float* __restrict__ gw0,
                                                              const float* __restrict__ gw1,
                                                              float* __restrict__ g0,
                                                              float* __restrict__ g1)
{
    __shared__ float sA[NF * 17];
    __shared__ float sG0[NF * 3];
    __shared__ float sG1[NF * 3];

    int tid  = threadIdx.x;
    int row0 = blockIdx.x * 16;

    build_rows1024(p0, p1, cnt, nbr, skip, awr, sA, row0, tid);
    for (int idx = tid; idx < NF * 3; idx += 1024) {
        sG0[idx] = gw0[idx];
        sG1[idx] = gw1[idx];
    }
    __syncthreads();

    if (tid < 96) {
        int row  = tid / 6;
        int rem  = tid % 6;
        int head = rem / 3;
        int col  = rem % 3;
        const float* gw = head ? sG1 : sG0;
        float s = 0.f;
        for (int k = 0; k < NF; ++k)
            s += sA[k * 17 + row] * gw[k * 3 + col];
        (head ? g1 : g0)[(size_t)(row0 + row) * 3 + col] = s;
    }
}

// ============ out0 = pos + tanh(relu(g0 + A g1)) ============
__global__ __launch_bounds__(256) void gc2_kernel(const float* __restrict__ g0,
                                                  const float* __restrict__ g1,
                                                  const int* __restrict__ cnt,
                                                  const int* __restrict__ nbr,
                                                  const float* __restrict__ pos,
                                                  float* __restrict__ out0)
{
    int idx = blockIdx.x * 256 + threadIdx.x;
    if (idx >= N_V * 3) return;
    int n = idx / 3, c0 = idx % 3;
    float s = g0[idx];
    int c = cnt[n];
    const int* nb = nbr + (size_t)n * CAP;
    for (int i = 0; i < c; ++i)
        s += g1[(size_t)nb[i] * 3 + c0];
    s = fmaxf(s, 0.f);
    out0[idx] = pos[idx] + tanhf(s);
}

// ---------------- launcher: 9 dispatches, csr split across both prologue kernels ----------------
extern "C" void kernel_launch(void* const* d_in, const int* in_sizes, int n_in,
                              void* d_out, int out_size, void* d_ws, size_t ws_size,
                              hipStream_t stream)
{
    const float* f0     = (const float*)d_in[0];
    const float* f1     = (const float*)d_in[1];
    const float* f2     = (const float*)d_in[2];
    const float* f3     = (const float*)d_in[3];
    const float* adj    = (const float*)d_in[4];
    const float* pos    = (const float*)d_in[5];
    const float* vfeat  = (const float*)d_in[6];
    const float* lin_w  = (const float*)d_in[7];
    const float* rg0_c0_w0 = (const float*)d_in[8];
    const float* rg0_c0_w1 = (const float*)d_in[9];
    const float* rg0_c1_w0 = (const float*)d_in[10];
    const float* rg0_c1_w1 = (const float*)d_in[11];
    const float* rg0_proj  = (const float*)d_in[12];
    const float* rg1_c0_w0 = (const float*)d_in[13];
    const float* rg1_c0_w1 = (const float*)d_in[14];
    const float* rg1_c1_w0 = (const float*)d_in[15];
    const float* rg1_c1_w1 = (const float*)d_in[16];
    const float* rg2_c0_w0 = (const float*)d_in[17];
    const float* rg2_c0_w1 = (const float*)d_in[18];
    const float* rg2_c1_w0 = (const float*)d_in[19];
    const float* rg2_c1_w1 = (const float*)d_in[20];
    const float* gc_w0     = (const float*)d_in[21];
    const float* gc_w1     = (const float*)d_in[22];

    float* out0 = (float*)d_out;                       // (N,3)  pos+delta
    float* out1 = (float*)d_out + (size_t)N_V * 3;     // (N,128) final x

    // workspace layout (bytes), all 256-aligned; ~35.5 MB
    char* ws = (char*)d_ws;
    int*   cnt     = (int*)  (ws + 4096);
    int*   nbr     = (int*)  (ws + 65536);
    float* table   = (float*)(ws + 3211264);
    float* partial = (float*)(ws + 4816896);
    unsigned short* WHu = (unsigned short*)(ws + 9031680);
    unsigned short* WLu = (unsigned short*)(ws + 9580544);
    float* t0      = (float*)(ws + 10129408);
    float* t1      = (float*)(ws + 14323712);
    float* u0      = (float*)(ws + 18518016);
    float* u1      = (float*)(ws + 22712320);
    float* skipb   = (float*)(ws + 26906624);
    float* xb      = (float*)(ws + 31100928);
    float* g0      = (float*)(ws + 35295232);
    float* g1      = (float*)(ws + 35393536);

    prep_csrA_kernel<<<835, 512, 0, stream>>>(adj, cnt, nbr, f0, f1, f2, f3, lin_w, table, partial,
                                              rg0_c0_w0, rg0_c0_w1, rg0_proj,
                                              rg0_c1_w0, rg0_c1_w1,
                                              rg1_c0_w0, rg1_c0_w1, rg1_c1_w0, rg1_c1_w1,
                                              rg2_c0_w0, rg2_c0_w1, rg2_c1_w0, rg2_c1_w1,
                                              WHu, WLu);
    align_csrB_kernel<<<960, 512, 0, stream>>>(adj, cnt, nbr, pos, vfeat, table, partial,
                                               WHu, WLu, t0, t1, skipb);
    fgemm_kernel<<<512, 1024, 0, stream>>>(t0, t1, cnt, nbr, nullptr, nullptr, WHu, WLu, 0 * 2048, 1 * 2048, u0, u1);
    fgemm_kernel<<<512, 1024, 0, stream>>>(u0, u1, cnt, nbr, skipb, xb, WHu, WLu, 2 * 2048, 3 * 2048, t0, t1);
    fgemm_kernel<<<512, 1024, 0, stream>>>(t0, t1, cnt, nbr, nullptr, nullptr, WHu, WLu, 4 * 2048, 5 * 2048, u0, u1);
    fgemm_kernel<<<512, 1024, 0, stream>>>(u0, u1, cnt, nbr, xb, xb, WHu, WLu, 6 * 2048, 7 * 2048, t0, t1);
    fgemm_kernel<<<512, 1024, 0, stream>>>(t0, t1, cnt, nbr, nullptr, nullptr, WHu, WLu, 8 * 2048, 9 * 2048, u0, u1);
    fgemm_final_kernel<<<512, 1024, 0, stream>>>(u0, u1, cnt, nbr, xb, out1, gc_w0, gc_w1, g0, g1);
    gc2_kernel<<<(N_V * 3 + 255) / 256, 256, 0, stream>>>(g0, g1, cnt, nbr, pos, out0);
}

// Round 15
// 167.134 us; speedup vs baseline: 1.0489x; 1.0489x over previous
//
#include <hip/hip_runtime.h>

#define N_V   8192
#define CAP   96          // max neighbors kept (deg ~Binom(8192,16/8192): mean 16; P(>=96)~0)
#define NF    128
#define TBL_PROWS 1029    // partial rows: L1 784 + L2 196 + L3 49

typedef __attribute__((ext_vector_type(4))) float f32x4;
typedef __attribute__((ext_vector_type(8))) short b16x8;

__device__ __forceinline__ short f2bf(float f) {
    unsigned u = __builtin_bit_cast(unsigned, f);
    unsigned r = u + 0x7FFFu + ((u >> 16) & 1u);
    return (short)(r >> 16);
}
__device__ __forceinline__ float bf2f(short h) {
    return __builtin_bit_cast(float, ((unsigned)(unsigned short)h) << 16);
}
__device__ __forceinline__ float4 f4add(float4 a, float4 b) {
    return make_float4(a.x + b.x, a.y + b.y, a.z + b.z, a.w + b.w);
}

// ---- shared csr row-scan body: one wave processes row n ----
__device__ __forceinline__ void csr_row(const float* __restrict__ adj,
                                        int* __restrict__ cnt,
                                        int* __restrict__ nbr,
                                        int n, int lane)
{
    const float4* r4 = reinterpret_cast<const float4*>(adj + (size_t)n * N_V);
    int* row = nbr + (size_t)n * CAP;
    int base = 0;
    unsigned long long below = (1ull << lane) - 1ull;
    for (int it = 0; it < N_V / 256; ++it) {
        float4 v = r4[it * 64 + lane];
        unsigned long long m0 = __ballot(v.x != 0.f);
        unsigned long long m1 = __ballot(v.y != 0.f);
        unsigned long long m2 = __ballot(v.z != 0.f);
        unsigned long long m3 = __ballot(v.w != 0.f);
        int p = base + __popcll(m0 & below) + __popcll(m1 & below)
                     + __popcll(m2 & below) + __popcll(m3 & below);
        int col = it * 256 + lane * 4;
        if (v.x != 0.f && p < CAP) row[p++] = col;
        if (v.y != 0.f && p < CAP) row[p++] = col + 1;
        if (v.z != 0.f && p < CAP) row[p++] = col + 2;
        if (v.w != 0.f && p < CAP) row[p++] = col + 3;
        base += __popcll(m0) + __popcll(m1) + __popcll(m2) + __popcll(m3);
    }
    if (lane == 0) cnt[n] = (base < CAP) ? base : CAP;
}

// ============ kernel A: csr rows 0..4607 (blocks 0..575, 8 rows) | table GEMM (576..767) | wprep (768..834) ============
__global__ __launch_bounds__(512, 8) void prep_csrA_kernel(const float* __restrict__ adj,
                                                           int* __restrict__ cnt,
                                                           int* __restrict__ nbr,
                                                           const float* __restrict__ f0,
                                                           const float* __restrict__ f1,
                                                           const float* __restrict__ f2,
                                                           const float* __restrict__ f3,
                                                           const float* __restrict__ lin_w,
                                                           float* __restrict__ table,
                                                           float* __restrict__ partial,
                                                           const float* rg0_c0_w0, const float* rg0_c0_w1, const float* rg0_proj,
                                                           const float* rg0_c1_w0, const float* rg0_c1_w1,
                                                           const float* rg1_c0_w0, const float* rg1_c0_w1,
                                                           const float* rg1_c1_w0, const float* rg1_c1_w1,
                                                           const float* rg2_c0_w0, const float* rg2_c0_w1,
                                                           const float* rg2_c1_w0, const float* rg2_c1_w1,
                                                           unsigned short* __restrict__ WHu,
                                                           unsigned short* __restrict__ WLu)
{
    __shared__ __align__(16) float sF[32][36];
    __shared__ __align__(16) float sW[32][NF];

    int tid  = threadIdx.x;
    int wv   = tid >> 6, lane = tid & 63;

    if (blockIdx.x < 576) {
        csr_row(adj, cnt, nbr, blockIdx.x * 8 + wv, lane);
        return;
    }

    if (blockIdx.x < 768) {
        // ---- table split-K GEMM, 512-thread layout (2 p-rows/thread) ----
        int b = blockIdx.x - 576;
        int l, pb, kc;
        if      (b < 98)  { l = 0; pb = b;       kc = 0;                     }
        else if (b < 148) { int t = b - 98;  l = 1; pb = t >> 1; kc = t & 1; }
        else if (b < 176) { int t = b - 148; l = 2; pb = t >> 2; kc = t & 3; }
        else              { int t = b - 176; l = 3; pb = t >> 3; kc = t & 7; }
        const float* f = (l == 0) ? f0 : (l == 1) ? f1 : (l == 2) ? f2 : f3;
        int P      = (l == 0) ? 3136 : (l == 1) ? 784 : (l == 2) ? 196 : 49;
        int rowoff = (l == 0) ? 0 : (l == 1) ? 256 : (l == 2) ? 768 : 1792;
        int rel0   = (l == 1) ? 0 : (l == 2) ? 784 : 980;
        int p0c    = pb * 32;
        int kbeg   = kc * 256;

        int ty = tid >> 5;             // 0..15 -> 2 p each
        int tx = tid & 31;             // 4 j each
        float4 acc0 = make_float4(0.f, 0.f, 0.f, 0.f), acc1 = acc0;

        #pragma unroll 1
        for (int ks = 0; ks < 8; ++ks) {
            int k0 = kbeg + ks * 32;
            #pragma unroll
            for (int t2 = 0; t2 < 2; ++t2) {
                int idx = tid + t2 * 512;
                int c = idx >> 5, pp = idx & 31;
                int p = p0c + pp;
                sF[c][pp] = (p < P) ? f[(size_t)(k0 + c) * P + p] : 0.f;
            }
            {
                const float4* lw4 = (const float4*)(lin_w + (size_t)(rowoff + k0) * NF);
                #pragma unroll
                for (int t2 = 0; t2 < 2; ++t2) {
                    int idx = tid + t2 * 512;
                    int kr = idx >> 5, c4 = idx & 31;
                    *(float4*)&sW[kr][c4 * 4] = lw4[(size_t)kr * 32 + c4];
                }
            }
            __syncthreads();
            #pragma unroll
            for (int kk = 0; kk < 32; ++kk) {
                float4 wv4 = *(const float4*)&sW[kk][tx * 4];
                float a0 = sF[kk][ty * 2];
                float a1 = sF[kk][ty * 2 + 1];
                acc0.x += a0 * wv4.x; acc0.y += a0 * wv4.y; acc0.z += a0 * wv4.z; acc0.w += a0 * wv4.w;
                acc1.x += a1 * wv4.x; acc1.y += a1 * wv4.y; acc1.z += a1 * wv4.z; acc1.w += a1 * wv4.w;
            }
            __syncthreads();
        }
        #pragma unroll
        for (int i = 0; i < 2; ++i) {
            int p = p0c + ty * 2 + i;
            if (p < P) {
                float4 o = i ? acc1 : acc0;
                if (l == 0) *(float4*)&table[(size_t)p * NF + tx * 4] = o;
                else        *(float4*)&partial[((size_t)kc * TBL_PROWS + rel0 + p) * NF + tx * 4] = o;
            }
        }
        return;
    }

    // ---- weight prep: split-bf16, MFMA-frag order (one task per block, 512-thread stride) ----
    {
        const float* k128s[10] = { rg0_c1_w0, rg0_c1_w1, rg1_c0_w0, rg1_c0_w1, rg1_c1_w0,
                                   rg1_c1_w1, rg2_c0_w0, rg2_c0_w1, rg2_c1_w0, rg2_c1_w1 };
        const float* k288s[3]  = { rg0_c0_w0, rg0_c0_w1, rg0_proj };
        int b = blockIdx.x - 768;
        const float* src;
        int K, ks;
        size_t dst;
        if (b < 40) { int m = b >> 2; ks = b & 3;              src = k128s[m]; K = 128; dst = (size_t)m * 16384 + (size_t)ks * 4096; }
        else        { int t = b - 40; int m = t / 9; ks = t % 9; src = k288s[m]; K = 259; dst = 163840 + (size_t)m * 36864 + (size_t)ks * 4096; }
        for (int idx = tid; idx < 4096; idx += 512) {
            int lane2 = (idx >> 3) & 63;
            int i     = idx & 7;
            int nt    = idx >> 9;
            int sk = ks * 32 + ((lane2 >> 4) << 3) + i;
            int sn = (nt << 4) + (lane2 & 15);
            float v = (sk < K) ? src[(size_t)sk * NF + sn] : 0.f;
            short hh = f2bf(v);
            short ll = f2bf(v - bf2f(hh));
            WHu[dst + idx] = (unsigned short)hh;
            WLu[dst + idx] = (unsigned short)ll;
        }
    }
}

// ============ kernel B: csr rows 4608..8191 (blocks 0..447) | a3align (448..959, 16 rows) ============
__global__ __launch_bounds__(512, 8) void align_csrB_kernel(const float* __restrict__ adj,
                                                            int* __restrict__ cnt,
                                                            int* __restrict__ nbr,
                                                            const float* __restrict__ pos,
                                                            const float* __restrict__ vfeat,
                                                            const float* __restrict__ table,
                                                            const float* __restrict__ partial,
                                                            const unsigned short* __restrict__ WHu,
                                                            const unsigned short* __restrict__ WLu,
                                                            float* __restrict__ t0,
                                                            float* __restrict__ t1,
                                                            float* __restrict__ skipb)
{
    __shared__ float sMem[288 * 17];   // 19.6 KB
    __shared__ int   sIdx[16][4];

    int tid = threadIdx.x;
    int wv  = tid >> 6, lane = tid & 63;

    if (blockIdx.x < 448) {
        csr_row(adj, cnt, nbr, 4608 + blockIdx.x * 8 + wv, lane);
        return;
    }

    int row0 = (blockIdx.x - 448) * 16;

    if (tid < 16) {
        int n = row0 + tid;
        float px = pos[(size_t)n * 3 + 0];
        float py = pos[(size_t)n * 3 + 1];
        float pz = pos[(size_t)n * 3 + 2];
        float h = fminf(fmaxf(__fadd_rn(__fmul_rn(248.f, __fdiv_rn(py, pz)),  111.5f), 0.f), 223.f);
        float w = fminf(fmaxf(__fadd_rn(__fmul_rn(248.f, __fdiv_rn(px, -pz)), 111.5f), 0.f), 223.f);
        const int   sxs[4]   = {56, 28, 14, 7};
        const float scl[4]   = {0.25f, 0.125f, 0.0625f, 0.03125f};
        const int   rel0s[4] = {0, 0, 784, 980};
        #pragma unroll
        for (int l = 0; l < 4; ++l) {
            float x = __fmul_rn(w, scl[l]);
            float y = __fmul_rn(h, scl[l]);
            int x1 = (int)floorf(x);
            int x2 = min((int)ceilf(x), sxs[l] - 1);
            int y1 = (int)floorf(y);
            int y2 = min((int)ceilf(y), sxs[l] - 1);
            int xi = (int)x, yi = (int)y;
            int w11 = (x2 - xi) * (y2 - yi);   // in {0,1}
            sIdx[tid][l] = w11 ? (rel0s[l] + x1 * sxs[l] + y1) : -1;
        }
    }
    __syncthreads();
    {
        // coalesced assemble: lane-contiguous c, row r = tid>>5
        int r = tid >> 5, cb = tid & 31;
        int n = row0 + r;
        #pragma unroll 1
        for (int k = 0; k < 9; ++k) {
            int c = cb + k * 32;               // 0..287
            float val;
            if (c < 128) {
                val = vfeat[(size_t)n * NF + c];
            } else if (c < 131) {
                val = pos[(size_t)n * 3 + (c - 128)];
            } else if (c < 259) {
                int jj = c - 131;
                val = 0.f;
                int i0 = sIdx[r][0];
                if (i0 >= 0) val += table[(size_t)i0 * NF + jj];
                #pragma unroll
                for (int l = 1; l < 4; ++l) {
                    int ix = sIdx[r][l];
                    if (ix >= 0) {
                        int nc = (l == 1) ? 2 : (l == 2) ? 4 : 8;
                        for (int cc = 0; cc < nc; ++cc)
                            val += partial[((size_t)cc * TBL_PROWS + ix) * NF + jj];
                    }
                }
            } else {
                val = 0.f;
            }
            sMem[c * 17 + r] = val;
        }
    }
    __syncthreads();
    // 6 waves: (head 0..2) x (nhalf 0..1), 4 nt tiles each
    if (wv < 6) {
        int head = wv >> 1, nh = wv & 1;
        const b16x8* Bh = (const b16x8*)WHu + 20480 + head * 4608;
        const b16x8* Bl = (const b16x8*)WLu + 20480 + head * 4608;
        float* O = (head == 0) ? t0 : (head == 1) ? t1 : skipb;
        f32x4 acc[4] = {};
        int m  = lane & 15;
        int kb = (lane >> 4) << 3;
        #pragma unroll 1
        for (int ks = 0; ks < 9; ++ks) {
            b16x8 va, vl;
            #pragma unroll
            for (int i = 0; i < 8; ++i) {
                float f = sMem[(ks * 32 + kb + i) * 17 + m];
                short hi = f2bf(f);
                va[i] = hi;
                vl[i] = f2bf(f - bf2f(hi));
            }
            #pragma unroll
            for (int t = 0; t < 4; ++t) {
                int nt = nh * 4 + t;
                b16x8 bh = Bh[(ks * 8 + nt) * 64 + lane];
                b16x8 bl = Bl[(ks * 8 + nt) * 64 + lane];
                acc[t] = __builtin_amdgcn_mfma_f32_16x16x32_bf16(va, bh, acc[t], 0, 0, 0);
                acc[t] = __builtin_amdgcn_mfma_f32_16x16x32_bf16(vl, bh, acc[t], 0, 0, 0);
                acc[t] = __builtin_amdgcn_mfma_f32_16x16x32_bf16(va, bl, acc[t], 0, 0, 0);
            }
        }
        int orow = row0 + ((lane >> 4) << 2);
        int oc   = lane & 15;
        #pragma unroll
        for (int t = 0; t < 4; ++t)
            #pragma unroll
            for (int rr = 0; rr < 4; ++rr)
                O[(size_t)(orow + rr) * NF + (nh * 4 + t) * 16 + oc] = acc[t][rr];
    }
}

// ---- build 16-row A-tile, COALESCED + index-preload: 512 threads = 16 rows x 32 lanes/row ----
// All 6 int4 index groups (covers deg<=24, ~98% rows) load unconditionally at entry -> one round trip,
// concurrent with cnt. Named registers (no runtime-indexed array -> no scratch). Guarded use only.
__device__ __forceinline__ void build_rows512(const float* __restrict__ p0,
                                              const float* __restrict__ p1,
                                              const int* __restrict__ cnt,
                                              const int* __restrict__ nbr,
                                              const float* skip,
                                              float* awr,
                                              float* sA, int row0, int tid)
{
    int r  = tid >> 5;                  // 0..15 row
    int ch = tid & 31;                  // 0..31 -> float4 col (contiguous across lanes)
    int n  = row0 + r;
    const int*  nb  = nbr + (size_t)n * CAP;
    const int4* nb4 = (const int4*)nb;
    // issue everything up-front: cnt, 6 index quads, p0 row
    int cdeg = cnt[n];
    int4 q0 = nb4[0], q1 = nb4[1], q2 = nb4[2], q3 = nb4[3], q4 = nb4[4], q5 = nb4[5];
    float4 a = ((const float4*)(p0 + (size_t)n * NF))[ch];
    float4 b = make_float4(0.f, 0.f, 0.f, 0.f), c = b, d = b;

#define GATHER4(Q)                                                             \
    {                                                                          \
        float4 va = ((const float4*)(p1 + (size_t)(Q).x * NF))[ch];            \
        float4 vb = ((const float4*)(p1 + (size_t)(Q).y * NF))[ch];            \
        float4 vc = ((const float4*)(p1 + (size_t)(Q).z * NF))[ch];            \
        float4 vd = ((const float4*)(p1 + (size_t)(Q).w * NF))[ch];            \
        a = f4add(a, va);                                                      \
        b = f4add(b, vb);                                                      \
        c = f4add(c, vc);                                                      \
        d = f4add(d, vd);                                                      \
    }
    if (cdeg >= 4)  GATHER4(q0);
    if (cdeg >= 8)  GATHER4(q1);
    if (cdeg >= 12) GATHER4(q2);
    if (cdeg >= 16) GATHER4(q3);
    if (cdeg >= 20) GATHER4(q4);
    if (cdeg >= 24) GATHER4(q5);
#undef GATHER4
    int i = (cdeg < 24) ? (cdeg & ~3) : 24;
    for (; i < cdeg; ++i)
        a = f4add(a, ((const float4*)(p1 + (size_t)nb[i] * NF))[ch]);
    a = f4add(f4add(a, b), f4add(c, d));
    float v[4] = { a.x, a.y, a.z, a.w };
    #pragma unroll
    for (int j = 0; j < 4; ++j) v[j] = fmaxf(v[j], 0.f);
    if (skip) {
        const float* rs = skip + (size_t)n * NF + ch * 4;
        #pragma unroll
        for (int j = 0; j < 4; ++j) v[j] += rs[j];
    }
    if (awr) {
        float* wr = awr + (size_t)n * NF + ch * 4;
        #pragma unroll
        for (int j = 0; j < 4; ++j) wr[j] = v[j];
    }
    #pragma unroll
    for (int j = 0; j < 4; ++j) sA[(ch * 4 + j) * 17 + r] = v[j];
}

// ============ fused SpMM + 2-head MFMA (512 blocks x 512 thr) ============
__global__ __launch_bounds__(512, 4) void fgemm_kernel(const float* __restrict__ p0,
                                                       const float* __restrict__ p1,
                                                       const int* __restrict__ cnt,
                                                       const int* __restrict__ nbr,
                                                       const float* __restrict__ skip,
                                                       float* __restrict__ awr,
                                                       const unsigned short* __restrict__ WHu,
                                                       const unsigned short* __restrict__ WLu,
                                                       int fo0, int fo1,
                                                       float* __restrict__ O0,
                                                       float* __restrict__ O1)
{
    __shared__ float sA[NF * 17];      // 8.7 KB
    int tid  = threadIdx.x;
    int row0 = blockIdx.x * 16;
    build_rows512(p0, p1, cnt, nbr, skip, awr, sA, row0, tid);
    __syncthreads();

    int wv = tid >> 6, lane = tid & 63;
    int h  = wv >> 2;                  // 0..1
    int nq = wv & 3;                   // 0..3 -> nt = nq*2 + t
    int fo = h ? fo1 : fo0;
    const b16x8* Bh = (const b16x8*)WHu + fo;
    const b16x8* Bl = (const b16x8*)WLu + fo;
    float* O = h ? O1 : O0;
    f32x4 acc[2] = {};
    int m  = lane & 15;
    int kb = (lane >> 4) << 3;
    #pragma unroll 1
    for (int ks = 0; ks < 4; ++ks) {
        b16x8 va, vl;
        #pragma unroll
        for (int i = 0; i < 8; ++i) {
            float f = sA[(ks * 32 + kb + i) * 17 + m];
            short hi = f2bf(f);
            va[i] = hi;
            vl[i] = f2bf(f - bf2f(hi));
        }
        #pragma unroll
        for (int t = 0; t < 2; ++t) {
            int nt = nq * 2 + t;
            b16x8 bh = Bh[(ks * 8 + nt) * 64 + lane];
            b16x8 bl = Bl[(ks * 8 + nt) * 64 + lane];
            acc[t] = __builtin_amdgcn_mfma_f32_16x16x32_bf16(va, bh, acc[t], 0, 0, 0);
            acc[t] = __builtin_amdgcn_mfma_f32_16x16x32_bf16(vl, bh, acc[t], 0, 0, 0);
            acc[t] = __builtin_amdgcn_mfma_f32_16x16x32_bf16(va, bl, acc[t], 0, 0, 0);
        }
    }
    int orow = row0 + ((lane >> 4) << 2);
    int oc   = lane & 15;
    #pragma unroll
    for (int t = 0; t < 2; ++t)
        #pragma unroll
        for (int rr = 0; rr < 4; ++rr)
            O[(size_t)(orow + rr) * NF + (nq * 2 + t) * 16 + oc] = acc[t][rr];
}

// ============ final: x3 -> out1; g0 = x3@gw0, g1 = x3@gw1 ============
__global__ __launch_bounds__(512, 4) void fgemm_final_kernel(const float* __restrict__ p0,
                                                             const float* __restrict__ p1,
                                                             const int* __restrict__ cnt,
                                                             const int* __restrict__ nbr,
                                                             const float* __restrict__ skip,
                                                             float* __restrict__ awr,   // out1
                                                             const float* __restrict__ gw0,
                                                             const float* __restrict__ gw1,
                                                             float* __restrict__ g0,
                                                             float* __restrict__ g1)
{
    __shared__ float sA[NF * 17];
    __shared__ float sG0[NF * 3];
    __shared__ float sG1[NF * 3];

    int tid  = threadIdx.x;
    int row0 = blockIdx.x * 16;

    build_rows512(p0, p1, cnt, nbr, skip, awr, sA, row0, tid);
    for (int idx = tid; idx < NF * 3; idx += 512) {
        sG0[idx] = gw0[idx];
        sG1[idx] = gw1[idx];
    }
    __syncthreads();

    if (tid < 96) {
        int row  = tid / 6;
        int rem  = tid % 6;
        int head = rem / 3;
        int col  = rem % 3;
        const float* gw = head ? sG1 : sG0;
        float s = 0.f;
        for (int k = 0; k < NF; ++k)
            s += sA[k * 17 + row] * gw[k * 3 + col];
        (head ? g1 : g0)[(size_t)(row0 + row) * 3 + col] = s;
    }
}

// ============ out0 = pos + tanh(relu(g0 + A g1)) ============
__global__ __launch_bounds__(256) void gc2_kernel(const float* __restrict__ g0,
                                                  const float* __restrict__ g1,
                                                  const int* __restrict__ cnt,
                                                  const int* __restrict__ nbr,
                                                  const float* __restrict__ pos,
                                                  float* __restrict__ out0)
{
    int idx = blockIdx.x * 256 + threadIdx.x;
    if (idx >= N_V * 3) return;
    int n = idx / 3, c0 = idx % 3;
    float s = g0[idx];
    int c = cnt[n];
    const int* nb = nbr + (size_t)n * CAP;
    for (int i = 0; i < c; ++i)
        s += g1[(size_t)nb[i] * 3 + c0];
    s = fmaxf(s, 0.f);
    out0[idx] = pos[idx] + tanhf(s);
}

// ---------------- launcher: 9 dispatches, csr split across both prologue kernels ----------------
extern "C" void kernel_launch(void* const* d_in, const int* in_sizes, int n_in,
                              void* d_out, int out_size, void* d_ws, size_t ws_size,
                              hipStream_t stream)
{
    const float* f0     = (const float*)d_in[0];
    const float* f1     = (const float*)d_in[1];
    const float* f2     = (const float*)d_in[2];
    const float* f3     = (const float*)d_in[3];
    const float* adj    = (const float*)d_in[4];
    const float* pos    = (const float*)d_in[5];
    const float* vfeat  = (const float*)d_in[6];
    const float* lin_w  = (const float*)d_in[7];
    const float* rg0_c0_w0 = (const float*)d_in[8];
    const float* rg0_c0_w1 = (const float*)d_in[9];
    const float* rg0_c1_w0 = (const float*)d_in[10];
    const float* rg0_c1_w1 = (const float*)d_in[11];
    const float* rg0_proj  = (const float*)d_in[12];
    const float* rg1_c0_w0 = (const float*)d_in[13];
    const float* rg1_c0_w1 = (const float*)d_in[14];
    const float* rg1_c1_w0 = (const float*)d_in[15];
    const float* rg1_c1_w1 = (const float*)d_in[16];
    const float* rg2_c0_w0 = (const float*)d_in[17];
    const float* rg2_c0_w1 = (const float*)d_in[18];
    const float* rg2_c1_w0 = (const float*)d_in[19];
    const float* rg2_c1_w1 = (const float*)d_in[20];
    const float* gc_w0     = (const float*)d_in[21];
    const float* gc_w1     = (const float*)d_in[22];

    float* out0 = (float*)d_out;                       // (N,3)  pos+delta
    float* out1 = (float*)d_out + (size_t)N_V * 3;     // (N,128) final x

    // workspace layout (bytes), all 256-aligned; ~35.5 MB
    char* ws = (char*)d_ws;
    int*   cnt     = (int*)  (ws + 4096);
    int*   nbr     = (int*)  (ws + 65536);
    float* table   = (float*)(ws + 3211264);
    float* partial = (float*)(ws + 4816896);
    unsigned short* WHu = (unsigned short*)(ws + 9031680);
    unsigned short* WLu = (unsigned short*)(ws + 9580544);
    float* t0      = (float*)(ws + 10129408);
    float* t1      = (float*)(ws + 14323712);
    float* u0      = (float*)(ws + 18518016);
    float* u1      = (float*)(ws + 22712320);
    float* skipb   = (float*)(ws + 26906624);
    float* xb      = (float*)(ws + 31100928);
    float* g0      = (float*)(ws + 35295232);
    float* g1      = (float*)(ws + 35393536);

    prep_csrA_kernel<<<835, 512, 0, stream>>>(adj, cnt, nbr, f0, f1, f2, f3, lin_w, table, partial,
                                              rg0_c0_w0, rg0_c0_w1, rg0_proj,
                                              rg0_c1_w0, rg0_c1_w1,
                                              rg1_c0_w0, rg1_c0_w1, rg1_c1_w0, rg1_c1_w1,
                                              rg2_c0_w0, rg2_c0_w1, rg2_c1_w0, rg2_c1_w1,
                                              WHu, WLu);
    align_csrB_kernel<<<960, 512, 0, stream>>>(adj, cnt, nbr, pos, vfeat, table, partial,
                                               WHu, WLu, t0, t1, skipb);
    fgemm_kernel<<<512, 512, 0, stream>>>(t0, t1, cnt, nbr, nullptr, nullptr, WHu, WLu, 0 * 2048, 1 * 2048, u0, u1);
    fgemm_kernel<<<512, 512, 0, stream>>>(u0, u1, cnt, nbr, skipb, xb, WHu, WLu, 2 * 2048, 3 * 2048, t0, t1);
    fgemm_kernel<<<512, 512, 0, stream>>>(t0, t1, cnt, nbr, nullptr, nullptr, WHu, WLu, 4 * 2048, 5 * 2048, u0, u1);
    fgemm_kernel<<<512, 512, 0, stream>>>(u0, u1, cnt, nbr, xb, xb, WHu, WLu, 6 * 2048, 7 * 2048, t0, t1);
    fgemm_kernel<<<512, 512, 0, stream>>>(t0, t1, cnt, nbr, nullptr, nullptr, WHu, WLu, 8 * 2048, 9 * 2048, u0, u1);
    fgemm_final_kernel<<<512, 512, 0, stream>>>(u0, u1, cnt, nbr, xb, out1, gc_w0, gc_w1, g0, g1);
    gc2_kernel<<<(N_V * 3 + 255) / 256, 256, 0, stream>>>(g0, g1, cnt, nbr, pos, out0);
}